// Round 13
// baseline (144.477 us; speedup 1.0000x reference)
//
#include <hip/hip_runtime.h>
#include <math.h>

// Problem: SphericalHarmonicTransform, L=8, RCUT=5, N=4194304 points.
// R22: FULL SCALARIZATION of the point body (no v_pk ops), z2 chain
//     truncated at k=4, h table restored.
//     Why: CDNA4 v_pk_fma_f32 occupies 4cyc (157.3TF = scalar rate -> no
//     packed throughput advantage), so the pk encoding pays VOP3P pair
//     constraints + marshalling movs for nothing. Busy-cycle count: pk
//     version ~1270 cyc/pt (reconstructs 66us at measured 51% busy);
//     scalar version ~898 cyc/pt (-29%): z2 chain only to k=4 (q<=3 and
//     m=0's dd[4] are all that's used - the packed chain wasted the z2
//     lane for k=5..8), Y built scalar (Yr=fmaf(-dd,dd,sqa)*cpq,
//     Yi=fmaf(aa,dd,bb*cc)*cpq = exact pk lanes), sums/folds as paired
//     scalar fmas (same FLOP-cycles, zero marshalling).
//     Bit-exact: per-value op sequences unchanged (R17 precedent: per-lane
//     scalarization held absmax 0.0); per-accumulator fold order unchanged.
//     DECISIVE FORK: if time ~ busy-cycles: main 66 -> 47-55us, bench ~115.
//     If time ~ raw instr count (516 vs 390): main ~80-85us -> revert and
//     declare pk encoding optimal / plateau structural.
//     Guards: VGPR 120-170 ok, WRITE ~2.6MB (spill -> revert), absmax 0.0.
// Harness facts: 41us unconditional 268MB d_ws poison-fill in timed window;
//     dur = 41 + main + 4(fin) + ~17(gaps).
// Known-good: unroll-1 point loop (R13); load rotation (R20, ~3%); g_ws
//     (R18, neutral); (256,1).
// Known-dead knobs: occupancy (busy pinned ~50% at 2-2.5 waves, R9-R16);
//     dep-order/interchange (R21 neutral); unroll 2 (R19 spill); f32x4
//     2-pt packing (R12); pair-packed split (R17); (l,m) split (R16);
//     waves_per_eu (R10); (256,4) fat (R2); fused finalize (R5).

#define NL 8               // L
#define NBLK 1024
#define NTHR 256

// module-scope scratch: replaces d_ws (neutral vs d_ws, kept).
__device__ float g_ws[81 * NBLK];

__device__ __forceinline__ float waveReduce(float v) {
    v += __shfl_down(v, 32);
    v += __shfl_down(v, 16);
    v += __shfl_down(v, 8);
    v += __shfl_down(v, 4);
    v += __shfl_down(v, 2);
    v += __shfl_down(v, 1);
    return v;
}

// One point, all scalar. acc0[9] = m=0; accRe/accIm[36]: t(l,m)=l(l-1)/2+m-1.
// Every value's op sequence is the exact per-lane form of the R13..R21
// packed code -> bitwise-identical contributions.
__device__ __forceinline__ void point_body(float x, float y, float z,
                                           float* __restrict__ acc0,
                                           float* __restrict__ accRe,
                                           float* __restrict__ accIm) {
    const float FACT[9] = {1.f, 1.f, 2.f, 6.f, 24.f, 120.f, 720.f, 5040.f, 40320.f};

    const float r2 = x * x + y * y + z * z;
    const bool valid = r2 > 0.0f;
    const float inv0 = __builtin_amdgcn_rsqf(r2);      // 1/sqrt(r2)
    const float norm = r2 * inv0;                      // sqrt(r2); NaN at 0, masked
    float cut = 0.5f * (__cosf(norm * 0.6283185307179586f) + 1.0f);
    cut = (r2 > 25.0f) ? 0.0f : cut;
    cut = valid ? cut : 0.0f;                          // kills NaN at r2=0
    const float inv = valid ? inv0 : 1.0f;             // safe 1/norm
    const float x0c = z * cut;

    // z1 = (-x/2, -y/2) chain to k=8 (buggy reference recurrence, scalar =
    // per-lane form of the old packed chain -> identical values):
    //  k=2 -> (wr^2-wi^2, 2*wr*wi); ci(2) = wr*wi + wi*zr[2];
    //  k>=3 -> nr = wr*cr - wi*ci; ni = wr*ci + wi*nr (uses NEW nr).
    float aa[9], bb[9];
    {
        const float wr = -0.5f * x, wi = -0.5f * y;
        aa[0] = 1.f;  bb[0] = 0.f;
        aa[1] = wr;   bb[1] = wi;
        aa[2] = wr * wr - wi * wi;
        bb[2] = (wr + wr) * wi;
        float cr = aa[2];
        float ci = wr * wi + wi * cr;                  // buggy chain imag at k=2
#pragma unroll
        for (int k = 3; k <= NL; ++k) {
            const float nr = wr * cr - wi * ci;
            const float ni = wr * ci + wi * nr;        // buggy: uses nr
            cr = nr; ci = ni;
            aa[k] = nr; bb[k] = ni;
        }
    }
    // z2 = (x/2, -y/2) chain truncated at k=4 (max consumed index: q<=3 for
    // m>=1, dd[4] for m=0). Same recurrence -> prefix values identical.
    float cc[5], dd[5];
    {
        const float wr = 0.5f * x, wi = -0.5f * y;
        cc[0] = 1.f;  dd[0] = 0.f;
        cc[1] = wr;   dd[1] = wi;
        cc[2] = wr * wr - wi * wi;
        dd[2] = (wr + wr) * wi;
        float cr = cc[2];
        float ci = wr * wi + wi * cr;                  // buggy chain imag at k=2
#pragma unroll
        for (int k = 3; k <= 4; ++k) {
            const float nr = wr * cr - wi * ci;
            const float ni = wr * ci + wi * nr;        // buggy: uses nr
            cr = nr; ci = ni;
            cc[k] = nr; dd[k] = ni;
        }
    }

    float sqa[9];
#pragma unroll
    for (int p = 0; p <= NL; ++p) sqa[p] = aa[p] * aa[p];

    // h table: identical left-assoc chain h[l] = h[l-1]*inv (R13 form).
    float h[9];
    h[0] = x0c;
#pragma unroll
    for (int l = 1; l <= NL; ++l) h[l] = h[l - 1] * inv;

    // ---- m = 0 (p-outer; per-l p-ascending order preserved) ----
    {
        float sr[9];
#pragma unroll
        for (int l = 0; l <= NL; ++l) sr[l] = 0.f;
#pragma unroll
        for (int p = 0; p <= 4; ++p) {
            const float cpq = 1.0f / (FACT[p] * FACT[p]);       // compile-time
            const float Y0 = fmaf(-dd[p], dd[p], sqa[p]) * cpq;
#pragma unroll
            for (int l = 2 * p; l <= NL; ++l) {
                const float is = 1.0f / FACT[l - 2 * p];        // compile-time
                sr[l] = fmaf(Y0, is, sr[l]);
            }
        }
#pragma unroll
        for (int l = 0; l <= NL; ++l)
            acc0[l] = fmaf(sr[l], h[l], acc0[l]);
    }

    // ---- m >= 1 (p-outer; scalar re/im; per-accumulator order unchanged) --
#pragma unroll
    for (int m = 1; m <= NL; ++m) {
        float sr[9], si[9];
#pragma unroll
        for (int l = m; l <= NL; ++l) { sr[l] = 0.f; si[l] = 0.f; }
#pragma unroll
        for (int p = m; p <= NL; ++p) {
            if (2 * p - m <= NL) {
                const int q = p - m;                    // q <= 3
                const float cpq = 1.0f / (FACT[p] * FACT[q]);   // compile-time
                const float Yr = fmaf(-dd[q], dd[q], sqa[p]) * cpq;
                const float Yi = fmaf(aa[p], dd[q], bb[p] * cc[q]) * cpq;
#pragma unroll
                for (int l = 2 * p - m; l <= NL; ++l) {
                    const float is = 1.0f / FACT[l - 2 * p + m]; // compile-time
                    sr[l] = fmaf(Yr, is, sr[l]);
                    si[l] = fmaf(Yi, is, si[l]);
                }
            }
        }
#pragma unroll
        for (int l = m; l <= NL; ++l) {
            const int ai = l * (l - 1) / 2 + (m - 1);
            accRe[ai] = fmaf(sr[l], h[l], accRe[ai]);
            accIm[ai] = fmaf(si[l], h[l], accIm[ai]);
        }
    }
}

__global__ __launch_bounds__(256, 1)
void sht_main(const float* __restrict__ pos, int n) {
    float acc0[9], accRe[36], accIm[36];
#pragma unroll
    for (int i = 0; i < 9; ++i) acc0[i] = 0.f;
#pragma unroll
    for (int i = 0; i < 36; ++i) { accRe[i] = 0.f; accIm[i] = 0.f; }

    const int t = blockIdx.x * NTHR + threadIdx.x;
    const int nthreads = NBLK * NTHR;                       // 262144
    const int nchunks = (n / 8 + nthreads - 1) / nthreads;  // 2 for N=2^22

    // Same ownership & order as R9..R21 -> bit-identical accumulation.
    // Load rotation (R20): k+1's loads issue before k's body.
    for (int c = 0; c < nchunks; ++c) {
        const int idx = (c * nthreads + t) * 8;             // 8 contiguous points
        float nx, ny, nz;                                   // preloaded k=0
        if (idx < n) {
            nx = pos[3 * idx + 0];
            ny = pos[3 * idx + 1];
            nz = pos[3 * idx + 2];
        } else {
            nx = 0.f; ny = 0.f; nz = 0.f;                   // zero-pad: adds 0
        }
#pragma unroll 1
        for (int k = 0; k < 8; ++k) {
            const float x = nx, y = ny, z = nz;             // current point
            const int i2 = idx + k + 1;                     // next point
            if (k < 7 && i2 < n) {                          // issue next loads
                nx = pos[3 * i2 + 0];                       // early; waitcnt
                ny = pos[3 * i2 + 1];                       // lands next iter
                nz = pos[3 * i2 + 2];
            } else {
                nx = 0.f; ny = 0.f; nz = 0.f;
            }
            point_body(x, y, z, acc0, accRe, accIm);
        }
    }

    // ---- reduction: wave shuffle -> LDS across 4 waves -> per-block row ----
    __shared__ float red[81][5];   // [out slot][wave], padded stride
    const int lane = threadIdx.x & 63;
    const int wave = threadIdx.x >> 6;

#pragma unroll
    for (int l = 0; l <= NL; ++l) {
        float vr = waveReduce(acc0[l]);
        if (lane == 0) red[l * l + l][wave] = vr;
    }
#pragma unroll
    for (int m = 1; m <= NL; ++m) {
#pragma unroll
        for (int l = m; l <= NL; ++l) {
            const int ai = l * (l - 1) / 2 + (m - 1);
            float vr = waveReduce(accRe[ai]);
            if (lane == 0) red[l * l + l + m][wave] = vr;
            float vi = waveReduce(accIm[ai]);
            if (lane == 0) red[l * l + l - m][wave] = vi;
        }
    }
    __syncthreads();

    // transposed partials: g_ws[slot*NBLK + block]; every slot fully written
    // each launch before finalize reads -> no cross-iteration state.
    if ((int)threadIdx.x < 81) {
        float s = 0.f;
#pragma unroll
        for (int w = 0; w < 4; ++w) s += red[threadIdx.x][w];
        g_ws[threadIdx.x * NBLK + blockIdx.x] = s;
    }
}

__device__ double dfact(int nn) {
    double r = 1.0;
    for (int i = 2; i <= nn; ++i) r *= (double)i;
    return r;
}

// one block per output slot; 256 threads sum 1024 coalesced partials
__global__ __launch_bounds__(256)
void sht_finalize(float* __restrict__ out) {
    const int j = blockIdx.x;       // 0..80
    const int t = threadIdx.x;
    float s = 0.f;
#pragma unroll
    for (int k = 0; k < NBLK / 256; ++k)
        s += g_ws[j * NBLK + k * 256 + t];
    s = waveReduce(s);

    __shared__ float red[4];
    const int lane = t & 63, wave = t >> 6;
    if (lane == 0) red[wave] = s;
    __syncthreads();
    if (t == 0) {
        float tot = red[0] + red[1] + red[2] + red[3];
        int l = 0;
        while ((l + 1) * (l + 1) <= j) ++l;
        const int M = j - l * l - l;
        const int m = (M < 0) ? -M : M;
        // f = sqrt((l+m)!(l-m)!); k_l = sqrt((2l+1)/(4*3.14159))  (ref PI=3.14159)
        double sc = sqrt(dfact(l + m) * dfact(l - m)) *
                    sqrt((double)(2 * l + 1) / (4.0 * 3.14159));
        if (m > 0) sc *= sqrt(2.0) * ((m & 1) ? -1.0 : 1.0);
        out[j] = (float)((double)tot * sc);
    }
}

extern "C" void kernel_launch(void* const* d_in, const int* in_sizes, int n_in,
                              void* d_out, int out_size, void* d_ws, size_t ws_size,
                              hipStream_t stream) {
    const float* pos = (const float*)d_in[0];
    const int npts = in_sizes[0] / 3;
    float* out = (float*)d_out;
    (void)d_ws; (void)ws_size;     // unused (g_ws); the 268MB workspace fill
                                   // is unconditional either way (R18)

    sht_main<<<NBLK, NTHR, 0, stream>>>(pos, npts);
    sht_finalize<<<81, 256, 0, stream>>>(out);
}

// Round 14
// 131.961 us; speedup vs baseline: 1.0948x; 1.0948x over previous
//
#include <hip/hip_runtime.h>
#include <math.h>

// Problem: SphericalHarmonicTransform, L=8, RCUT=5, N=4194304 points.
// R23: R21 base (pk encoding, p-outer, load-rot) + two slot cuts:
//     (1) single htab[9] (8 muls) replaces the per-m hbase/hl running
//         chains (44 muls) -> -36 dependent muls/pt. Same left-assoc
//         chain -> bit-identical h values.
//     (2) m=0 sums packed over l-pairs {2j,2j+1}: identical p-participation
//         per pair (2p<=2j <=> 2p<=2j+1) -> 25 scalar fma -> 10 pkfma +
//         5 scalar, per-lane op order unchanged. m0 folds stay scalar.
//     Model (resolved by R22's decisive fork): time ~ instruction SLOTS;
//     3-src VOP3/VOP3P (fma/pkfma) ~ 4cyc slot regardless of packing
//     (RF-port), 2-src muls ~2cyc, independent ops hide in shadows.
//     pk = densest encoding (2 FMA / slot) - why R8/R12/R17/R22 all lost.
//     Predicted: main 66 -> 57-61us, bench ~124-128; VGPR 80-88.
//     Guards: occupancy >=24% (cliff seen at VGPR92->19.6%), WRITE ~2.6MB,
//     absmax 0.0. If flat: slot model dead -> declare plateau.
// Harness facts: 41us unconditional 268MB d_ws poison-fill in timed window;
//     dur = 41 + main + 4(fin) + ~17(gaps).
// Known-good: unroll-1 point loop (R13); load rotation (R20, ~3%); g_ws
//     (R18, neutral); (256,1); pk encoding (R22 fork).
// Known-dead: occupancy knobs (busy pinned ~50%); interchange (R21 neutral);
//     scalarization (R22 -20%); unroll 2 (R19 spill); f32x4 2-pt (R12);
//     pair-pack split (R17); (l,m) split (R16); waves_per_eu (R10);
//     (256,4) fat (R2); fused finalize (R5).

typedef float f32x2 __attribute__((ext_vector_type(2)));

#define NL 8               // L
#define NBLK 1024
#define NTHR 256

// module-scope scratch: replaces d_ws (neutral vs d_ws, kept).
__device__ float g_ws[81 * NBLK];

__device__ __forceinline__ f32x2 sp(float v) { return f32x2{v, v}; }

__device__ __forceinline__ f32x2 pkfma(f32x2 a, f32x2 b, f32x2 c) {
    return __builtin_elementwise_fma(a, b, c);
}

// a*b with an opaque SSA def (blocks table re-CSE). Bitwise-identical value.
__device__ __forceinline__ float omul(float a, float b) {
    float r = a * b;
    asm("" : "+v"(r));
    return r;
}

__device__ __forceinline__ float waveReduce(float v) {
    v += __shfl_down(v, 32);
    v += __shfl_down(v, 16);
    v += __shfl_down(v, 8);
    v += __shfl_down(v, 4);
    v += __shfl_down(v, 2);
    v += __shfl_down(v, 1);
    return v;
}

// One point. acc0 = m=0 reals (9); accp = m>=1 (re,im) pairs (36).
// Every per-value op sequence identical to R13..R21 -> bit-exact.
__device__ __forceinline__ void point_body(float x, float y, float z,
                                           float* __restrict__ acc0,
                                           f32x2* __restrict__ accp) {
    const float FACT[9] = {1.f, 1.f, 2.f, 6.f, 24.f, 120.f, 720.f, 5040.f, 40320.f};

    const float r2 = x * x + y * y + z * z;
    const bool valid = r2 > 0.0f;
    const float inv0 = __builtin_amdgcn_rsqf(r2);      // 1/sqrt(r2)
    const float norm = r2 * inv0;                      // sqrt(r2); NaN at 0, masked
    float cut = 0.5f * (__cosf(norm * 0.6283185307179586f) + 1.0f);
    cut = (r2 > 25.0f) ? 0.0f : cut;
    cut = valid ? cut : 0.0f;                          // kills NaN at r2=0
    const float inv = valid ? inv0 : 1.0f;             // safe 1/norm
    const float x0c = z * cut;

    // packed chains: lane0 = z1 (xp), lane1 = z2 (xm)
    const f32x2 w  = { -0.5f * x,  0.5f * x };         // (xpr, xmr)
    const f32x2 wi = { -0.5f * y, -0.5f * y };         // (xpi, xmi)

    // powcmplx replication (reference's buggy chain):
    f32x2 zr[9], zi[9];
    zr[0] = sp(1.f); zi[0] = sp(0.f);
    zr[1] = w;       zi[1] = wi;
    zr[2] = w * w - wi * wi;
    zi[2] = (w + w) * wi;                              // 2*wr*wi
    {
        f32x2 cr = zr[2];
        f32x2 ci = w * wi + wi * cr;                   // buggy chain imag at k=2
#pragma unroll
        for (int k = 3; k <= NL; ++k) {
            const f32x2 nr = w * cr - wi * ci;
            const f32x2 ni = w * ci + wi * nr;         // buggy: uses nr
            cr = nr; ci = ni;
            zr[k] = nr; zi[k] = ni;
        }
    }

    // unpack views (register aliases, free). No sqa table (R15 form).
    float aa[9], bb[9], cc[9], dd[9];
#pragma unroll
    for (int p = 0; p <= NL; ++p) {
        aa[p] = zr[p].x;   // z1r
        cc[p] = zr[p].y;   // z2r
        bb[p] = zi[p].x;   // z1i
        dd[p] = zi[p].y;   // z2i
    }

    // h table: ONE left-assoc chain htab[l] = htab[l-1]*inv (exact same
    // chain the old hbase/hl running products reproduced per-m) -> values
    // bit-identical; -36 dependent muls/point. omul-style barriers keep
    // the chain from being re-associated.
    float htab[9];
    htab[0] = x0c;
#pragma unroll
    for (int l = 1; l <= NL; ++l) {
        float hv = htab[l - 1] * inv;
        asm("" : "+v"(hv));
        htab[l] = hv;
    }

    // ---- m = 0: sums packed over l-pairs {2j, 2j+1} (identical p-set per
    // pair; per-lane p-ascending order preserved -> bit-exact), folds scalar.
    {
        f32x2 srp[4];                                   // lanes {l=2j, 2j+1}
        float sr8 = 0.f;
#pragma unroll
        for (int j = 0; j < 4; ++j) srp[j] = sp(0.f);
#pragma unroll
        for (int p = 0; p <= 4; ++p) {
            const float cpq = 1.0f / (FACT[p] * FACT[p]);       // compile-time
            const float Y0 = fmaf(-dd[p], dd[p], omul(aa[p], aa[p])) * cpq;
#pragma unroll
            for (int j = p; j < 4; ++j) {               // pair j needs p <= j
                const f32x2 isp = { 1.0f / FACT[2 * j - 2 * p],
                                    1.0f / FACT[2 * j + 1 - 2 * p] };
                srp[j] = pkfma(sp(Y0), isp, srp[j]);
            }
            sr8 = fmaf(Y0, 1.0f / FACT[8 - 2 * p], sr8);
        }
#pragma unroll
        for (int l = 0; l <= NL; ++l) {
            const float srl = (l == 8) ? sr8
                              : ((l & 1) ? srp[l >> 1].y : srp[l >> 1].x);
            acc0[l] = fmaf(srl, htab[l], acc0[l]);
        }
    }

    // ---- m >= 1: p-outer / l-inner, packed (real, imag) ----
#pragma unroll
    for (int m = 1; m <= NL; ++m) {
        f32x2 s[9];                                     // s[l], l=m..8
#pragma unroll
        for (int l = m; l <= NL; ++l) s[l] = sp(0.f);
#pragma unroll
        for (int p = m; p <= NL; ++p) {
            if (2 * p - m <= NL) {
                const int q = p - m;
                const float cpq = 1.0f / (FACT[p] * FACT[q]);   // compile-time
                const float bc = bb[p] * cc[q];
                const f32x2 A = { -dd[q], aa[p] };
                const f32x2 B = {  dd[q], dd[q] };
                const f32x2 C = { omul(aa[p], aa[p]), bc };
                const f32x2 Y = pkfma(A, B, C) * sp(cpq);
#pragma unroll
                for (int l = 2 * p - m; l <= NL; ++l) {
                    const float is = 1.0f / FACT[l - 2 * p + m]; // compile-time
                    s[l] = pkfma(Y, sp(is), s[l]);
                }
            }
        }
#pragma unroll
        for (int l = m; l <= NL; ++l) {
            // accp index: t(l,m) = l*(l-1)/2 + (m-1)
            const int ai = l * (l - 1) / 2 + (m - 1);
            accp[ai] = pkfma(s[l], sp(htab[l]), accp[ai]);
        }
    }
}

__global__ __launch_bounds__(256, 1)
void sht_main(const float* __restrict__ pos, int n) {
    float acc0[9];
    f32x2 accp[36];
#pragma unroll
    for (int i = 0; i < 9; ++i) acc0[i] = 0.f;
#pragma unroll
    for (int i = 0; i < 36; ++i) accp[i] = sp(0.f);

    const int t = blockIdx.x * NTHR + threadIdx.x;
    const int nthreads = NBLK * NTHR;                       // 262144
    const int nchunks = (n / 8 + nthreads - 1) / nthreads;  // 2 for N=2^22

    // Same ownership & order as R9..R21 -> bit-identical accumulation.
    // Load rotation (R20): k+1's loads issue before k's body.
    for (int c = 0; c < nchunks; ++c) {
        const int idx = (c * nthreads + t) * 8;             // 8 contiguous points
        float nx, ny, nz;                                   // preloaded k=0
        if (idx < n) {
            nx = pos[3 * idx + 0];
            ny = pos[3 * idx + 1];
            nz = pos[3 * idx + 2];
        } else {
            nx = 0.f; ny = 0.f; nz = 0.f;                   // zero-pad: adds 0
        }
#pragma unroll 1
        for (int k = 0; k < 8; ++k) {
            const float x = nx, y = ny, z = nz;             // current point
            const int i2 = idx + k + 1;                     // next point
            if (k < 7 && i2 < n) {                          // issue next loads
                nx = pos[3 * i2 + 0];                       // early; waitcnt
                ny = pos[3 * i2 + 1];                       // lands next iter
                nz = pos[3 * i2 + 2];
            } else {
                nx = 0.f; ny = 0.f; nz = 0.f;
            }
            point_body(x, y, z, acc0, accp);
        }
    }

    // ---- reduction: wave shuffle -> LDS across 4 waves -> per-block row ----
    __shared__ float red[81][5];   // [out slot][wave], padded stride
    const int lane = threadIdx.x & 63;
    const int wave = threadIdx.x >> 6;

#pragma unroll
    for (int l = 0; l <= NL; ++l) {
        float vr = waveReduce(acc0[l]);
        if (lane == 0) red[l * l + l][wave] = vr;
    }
#pragma unroll
    for (int m = 1; m <= NL; ++m) {
#pragma unroll
        for (int l = m; l <= NL; ++l) {
            const int ai = l * (l - 1) / 2 + (m - 1);
            float vr = waveReduce(accp[ai].x);
            if (lane == 0) red[l * l + l + m][wave] = vr;
            float vi = waveReduce(accp[ai].y);
            if (lane == 0) red[l * l + l - m][wave] = vi;
        }
    }
    __syncthreads();

    // transposed partials: g_ws[slot*NBLK + block]; every slot fully written
    // each launch before finalize reads -> no cross-iteration state.
    if ((int)threadIdx.x < 81) {
        float s = 0.f;
#pragma unroll
        for (int w = 0; w < 4; ++w) s += red[threadIdx.x][w];
        g_ws[threadIdx.x * NBLK + blockIdx.x] = s;
    }
}

__device__ double dfact(int nn) {
    double r = 1.0;
    for (int i = 2; i <= nn; ++i) r *= (double)i;
    return r;
}

// one block per output slot; 256 threads sum 1024 coalesced partials
__global__ __launch_bounds__(256)
void sht_finalize(float* __restrict__ out) {
    const int j = blockIdx.x;       // 0..80
    const int t = threadIdx.x;
    float s = 0.f;
#pragma unroll
    for (int k = 0; k < NBLK / 256; ++k)
        s += g_ws[j * NBLK + k * 256 + t];
    s = waveReduce(s);

    __shared__ float red[4];
    const int lane = t & 63, wave = t >> 6;
    if (lane == 0) red[wave] = s;
    __syncthreads();
    if (t == 0) {
        float tot = red[0] + red[1] + red[2] + red[3];
        int l = 0;
        while ((l + 1) * (l + 1) <= j) ++l;
        const int M = j - l * l - l;
        const int m = (M < 0) ? -M : M;
        // f = sqrt((l+m)!(l-m)!); k_l = sqrt((2l+1)/(4*3.14159))  (ref PI=3.14159)
        double sc = sqrt(dfact(l + m) * dfact(l - m)) *
                    sqrt((double)(2 * l + 1) / (4.0 * 3.14159));
        if (m > 0) sc *= sqrt(2.0) * ((m & 1) ? -1.0 : 1.0);
        out[j] = (float)((double)tot * sc);
    }
}

extern "C" void kernel_launch(void* const* d_in, const int* in_sizes, int n_in,
                              void* d_out, int out_size, void* d_ws, size_t ws_size,
                              hipStream_t stream) {
    const float* pos = (const float*)d_in[0];
    const int npts = in_sizes[0] / 3;
    float* out = (float*)d_out;
    (void)d_ws; (void)ws_size;     // unused (g_ws); the 268MB workspace fill
                                   // is unconditional either way (R18)

    sht_main<<<NBLK, NTHR, 0, stream>>>(pos, npts);
    sht_finalize<<<81, 256, 0, stream>>>(out);
}